// Round 14
// baseline (175.208 us; speedup 1.0000x reference)
//
#include <hip/hip_runtime.h>
#include <hip/hip_bf16.h>
#include <math.h>

// Problem constants
#define B_  1024
#define N_  32
#define D_  512
#define EPS_ 1e-5f

typedef __attribute__((ext_vector_type(8))) short bf16x8;   // 8 bf16 = 4 VGPRs
typedef __attribute__((ext_vector_type(4))) float f32x4;
using bf16 = __hip_bfloat16;
typedef unsigned int u32;
typedef const u32 __attribute__((address_space(1)))* gp_t;
typedef u32 __attribute__((address_space(3)))* sp_t;

// async global->LDS, 16 B per lane, lds dest = wave-uniform base + lane*16
static __device__ __forceinline__ void gload16(const void* g, void* s) {
  __builtin_amdgcn_global_load_lds((gp_t)g, (sp_t)s, 16, 0, 0);
}
static __device__ __forceinline__ void bar() {
  asm volatile("s_barrier" ::: "memory");
}

static __device__ __forceinline__ unsigned short f2bf(float f) {
  union { float f; u32 u; } c; c.f = f;
  u32 r = c.u + 0x7fff + ((c.u >> 16) & 1);   // RNE
  return (unsigned short)(r >> 16);
}
static __device__ __forceinline__ float bf2f(unsigned short h) {
  union { u32 u; float f; } c; c.u = ((u32)h) << 16;
  return c.f;
}

// ---------------------------------------------------------------------------
// Transpose + cast: in [mat][R][C] f32 -> out [mat][C][R] bf16. 64x64 tiles.
// (separate kernels again: r13's fused prep was latency-bound at 2.3 TB/s --
// heterogeneous block mix broke co-residency; separate kernels ran ~60us.)
// ---------------------------------------------------------------------------
__global__ __launch_bounds__(256) void transpose_cast_kernel(
    const float* __restrict__ in, bf16* __restrict__ out, int R, int C) {
  __shared__ unsigned short tile[64][65];
  const size_t mat = (size_t)blockIdx.z * (size_t)R * (size_t)C;
  const float* inp = in + mat;
  bf16* outp = out + mat;
  const int c0 = blockIdx.x * 64, r0 = blockIdx.y * 64;
  const int tr = threadIdx.x >> 4;          // 0..15
  const int tc = (threadIdx.x & 15) * 4;    // 0,4,..,60
#pragma unroll
  for (int i = 0; i < 4; ++i) {
    const int r = tr + i * 16;
    float4 v = *(const float4*)&inp[(size_t)(r0 + r) * C + c0 + tc];
    tile[r][tc + 0] = f2bf(v.x);
    tile[r][tc + 1] = f2bf(v.y);
    tile[r][tc + 2] = f2bf(v.z);
    tile[r][tc + 3] = f2bf(v.w);
  }
  __syncthreads();
#pragma unroll
  for (int i = 0; i < 2; ++i) {
    const int chunk = i * 256 + threadIdx.x;
    const int c = chunk >> 3, r8 = (chunk & 7) * 8;
    union { bf16x8 v; unsigned short u[8]; } pk;
#pragma unroll
    for (int k = 0; k < 8; ++k) pk.u[k] = tile[r8 + k][c];
    *(bf16x8*)&outp[(size_t)(c0 + c) * R + r0 + r8] = pk.v;
  }
}

// ---------------------------------------------------------------------------
// mix + LN via MFMA (verified r8 version, unchanged).
// ---------------------------------------------------------------------------
__global__ __launch_bounds__(256) void mix_ln_kernel(
    const float* __restrict__ z, const int* __restrict__ idx,
    const float* __restrict__ A, const float* __restrict__ gamma,
    const float* __restrict__ beta, bf16* __restrict__ x_ws,
    int* __restrict__ inv_ws) {
  __shared__ float As[32][32];      // As[k][n] = A[p[k]][n]
  __shared__ int   p[32];
  __shared__ float red1[4][32];
  __shared__ float red2[4][32];
  __shared__ float meanS[32];
  __shared__ float rstdS[32];

  const int b = blockIdx.x;
  const int t = threadIdx.x;
  const int lane = t & 63, wid = t >> 6;      // 4 waves
  const int llo = lane & 15, lhi = lane >> 4; // col-lane / row-group

  if (t < 32) {
    int v = idx[b * 32 + t];
    p[t] = v;
    inv_ws[b * 32 + v] = t;
  }
  __syncthreads();
#pragma unroll
  for (int i = 0; i < 4; ++i) {
    const int id = i * 256 + t;
    As[id >> 5][id & 31] = A[p[id >> 5] * 32 + (id & 31)];
  }
  __syncthreads();

  bf16x8 af[2];
#pragma unroll
  for (int nt = 0; nt < 2; ++nt) {
    union { bf16x8 v; unsigned short s[8]; } u;
#pragma unroll
    for (int j = 0; j < 8; ++j)
      u.s[j] = f2bf(As[lhi * 8 + j][nt * 16 + llo]);
    af[nt] = u.v;
  }

  const float* zb = z + (size_t)b * (N_ * D_) + (size_t)(lhi * 8) * D_ + llo;
  const f32x4 fz = {0.f, 0.f, 0.f, 0.f};
  f32x4 acc[2][8];
#pragma unroll
  for (int nt = 0; nt < 2; ++nt)
#pragma unroll
    for (int dt = 0; dt < 8; ++dt) acc[nt][dt] = fz;

#pragma unroll
  for (int h = 0; h < 2; ++h) {
    float zr[4][8];
#pragma unroll
    for (int dd = 0; dd < 4; ++dd)
#pragma unroll
      for (int j = 0; j < 8; ++j)
        zr[dd][j] = zb[j * D_ + ((wid * 8 + h * 4 + dd) * 16)];
#pragma unroll
    for (int dd = 0; dd < 4; ++dd) {
      const int dt = h * 4 + dd;
      union { bf16x8 v; unsigned short s[8]; } u;
#pragma unroll
      for (int j = 0; j < 8; ++j) u.s[j] = f2bf(zr[dd][j]);
      acc[0][dt] = __builtin_amdgcn_mfma_f32_16x16x32_bf16(af[0], u.v, acc[0][dt], 0, 0, 0);
      acc[1][dt] = __builtin_amdgcn_mfma_f32_16x16x32_bf16(af[1], u.v, acc[1][dt], 0, 0, 0);
    }
  }

  float s1[2][4], s2[2][4];
#pragma unroll
  for (int nt = 0; nt < 2; ++nt)
#pragma unroll
    for (int r = 0; r < 4; ++r) {
      float a = 0.f, q = 0.f;
#pragma unroll
      for (int dt = 0; dt < 8; ++dt) {
        float v = acc[nt][dt][r];
        a += v; q += v * v;
      }
#pragma unroll
      for (int mk = 1; mk < 16; mk <<= 1) {
        a += __shfl_xor(a, mk);
        q += __shfl_xor(q, mk);
      }
      s1[nt][r] = a; s2[nt][r] = q;
    }
  if (llo == 0) {
#pragma unroll
    for (int nt = 0; nt < 2; ++nt)
#pragma unroll
      for (int r = 0; r < 4; ++r) {
        const int n = nt * 16 + lhi * 4 + r;
        red1[wid][n] = s1[nt][r];
        red2[wid][n] = s2[nt][r];
      }
  }
  __syncthreads();
  if (t < 32) {
    float S1 = red1[0][t] + red1[1][t] + red1[2][t] + red1[3][t];
    float S2 = red2[0][t] + red2[1][t] + red2[2][t] + red2[3][t];
    float mean = S1 * (1.f / D_);
    float var  = S2 * (1.f / D_) - mean * mean;
    meanS[t] = mean;
    rstdS[t] = rsqrtf(var + EPS_);
  }
  __syncthreads();

  float gv[8], bev[8];
#pragma unroll
  for (int dt = 0; dt < 8; ++dt) {
    const int d = (wid * 8 + dt) * 16 + llo;
    gv[dt] = gamma[d]; bev[dt] = beta[d];
  }
#pragma unroll
  for (int nt = 0; nt < 2; ++nt)
#pragma unroll
    for (int r = 0; r < 4; ++r) {
      const int n = nt * 16 + lhi * 4 + r;
      const float mn = meanS[n], rs = rstdS[n];
      unsigned short* xrow = (unsigned short*)(x_ws + ((size_t)n * B_ + b) * D_);
#pragma unroll
      for (int dt = 0; dt < 8; ++dt) {
        const int d = (wid * 8 + dt) * 16 + llo;
        float v = (acc[nt][dt][r] - mn) * rs * gv[dt] + bev[dt];
        xrow[d] = f2bf(v);
      }
    }
}

// ---------------------------------------------------------------------------
// 256x256 GEMM core, BK=32, 8 waves, 64KB LDS, register-lean fragment set
// (av[2]+bv[4] only; Gray quadrant order (0,0)->(1,0)->(1,1)->(0,1)).
// launch_bounds(512,2): no forced VGPR cap (cap-128 caused scratch spills).
// r13 measured: both GEMMs combined ~79us (vs 108us r8) -- KEEP UNCHANGED.
// BK=32 rows = 64B: ds_read_b128 naturally bank-uniform, no swizzle.
// LDS: A parity p at p*16K (halves 8K = 128 rows); B at 32K + p*16K.
// Per subtile: 14 b128 reads, 32 MFMA (setprio), bar, stage s+2 (4 gload16),
// counted vmcnt(4), bar. Lookahead 2 subtiles.
// ---------------------------------------------------------------------------
#define STGA(P, H, S)                                                         \
  gload16(Ag + (size_t)((H) * 128) * KD + (S) * 32 + soff,                    \
          lds + (P) * 16384 + (H) * 8192 + dof)
#define STGB(P, H, S)                                                         \
  gload16(Bg + (size_t)((H) * 128) * KD + (S) * 32 + soff,                    \
          lds + 32768 + (P) * 16384 + (H) * 8192 + dof)

#define RDA(P, H) do {                                                        \
    const char* a_ = lds + (P) * 16384 + (H) * 8192;                          \
    av[0] = *(const bf16x8*)(a_ + (widA * 32 + llo) * 64 + k16);              \
    av[1] = *(const bf16x8*)(a_ + (widA * 32 + 16 + llo) * 64 + k16);         \
  } while (0)
#define RDB(P, H) do {                                                        \
    const char* b_ = lds + 32768 + (P) * 16384 + (H) * 8192;                  \
    _Pragma("unroll")                                                         \
    for (int fj = 0; fj < 4; ++fj)                                            \
      bv[fj] = *(const bf16x8*)(b_ + (widB * 64 + fj * 16 + llo) * 64 + k16); \
  } while (0)

#define MMA8(QR, QC) do {                                                     \
    __builtin_amdgcn_s_setprio(1);                                            \
    _Pragma("unroll")                                                         \
    for (int fi = 0; fi < 2; ++fi)                                            \
      _Pragma("unroll")                                                       \
      for (int fj = 0; fj < 4; ++fj)                                          \
        acc[QR][QC][fi][fj] = __builtin_amdgcn_mfma_f32_16x16x32_bf16(        \
            av[fi], bv[fj], acc[QR][QC][fi][fj], 0, 0, 0);                    \
    __builtin_amdgcn_s_setprio(0);                                            \
  } while (0)

#define VMC4() asm volatile("s_waitcnt vmcnt(4)" ::: "memory")
#define VMC0() asm volatile("s_waitcnt vmcnt(0)" ::: "memory")

#define SUBTILE(P, S) do {                                                    \
    bf16x8 av[2], bv[4];                                                      \
    RDB(P, 0); RDA(P, 0);                                                     \
    MMA8(0, 0);                                                               \
    RDA(P, 1);                                                                \
    MMA8(1, 0);                                                               \
    RDB(P, 1);                              /* A half1 still loaded */        \
    MMA8(1, 1);                                                               \
    RDA(P, 0);                                                                \
    MMA8(0, 1);                                                               \
    bar();                                   /* all waves consumed buffer P */\
    if ((S) + 2 < NS) {                                                       \
      STGA(P, 0, (S) + 2); STGA(P, 1, (S) + 2);                               \
      STGB(P, 0, (S) + 2); STGB(P, 1, (S) + 2);                               \
      VMC4();                                /* retire subtile S+1's units */ \
    } else { VMC0(); }                                                        \
    bar();                                   /* buffer P^1 (S+1) published */ \
  } while (0)

template <int KD, int NS>
static __device__ __forceinline__ void gemm_core(
    const bf16* __restrict__ Ag, const bf16* __restrict__ Bg,
    char* __restrict__ lds, f32x4 (&acc)[2][2][2][4], const int t) {
  const int lane = t & 63, wid = t >> 6;
  const int llo = lane & 15, lhi = lane >> 4;
  const int widA = wid & 3, widB = wid >> 2;
  const int k16 = lhi * 16;                            // k-slot byte offset
  const size_t soff = (size_t)(t >> 2) * KD + (t & 3) * 8;   // stage src (elems)
  const int dof = wid * 1024;                          // stage LDS dest (bytes)

  // prologue: stage subtiles 0 and 1 fully; wait for subtile 0
  STGA(0, 0, 0); STGA(0, 1, 0); STGB(0, 0, 0); STGB(0, 1, 0);
  STGA(1, 0, 1); STGA(1, 1, 1); STGB(1, 0, 1); STGB(1, 1, 1);
  VMC4();
  bar();

#pragma unroll 1
  for (int it = 0; it < NS / 2; ++it) {
    SUBTILE(0, 2 * it);
    SUBTILE(1, 2 * it + 1);
  }
}

// ---------------------------------------------------------------------------
// GEMM1: C[h][b] = W1t[h][:] . X[b][:] (K=512), bias+ELU -> H[b][h] bf16.
// 256x256 tile; epilogue via LDS in two compile-time 64KB passes.
// grid 512 = 32m*4hb*4bb, XCD-swizzled.
// ---------------------------------------------------------------------------
#define EPI(QC) do {                                                          \
    __syncthreads();                                                          \
    _Pragma("unroll")                                                         \
    for (int qr = 0; qr < 2; ++qr)                                            \
      _Pragma("unroll")                                                       \
      for (int fi = 0; fi < 2; ++fi) {                                        \
        const int h_loc = qr * 128 + (wid & 3) * 32 + fi * 16 + lhi * 4;      \
        const float4 bi = *(const float4*)&b1m[h_loc];                        \
        _Pragma("unroll")                                                     \
        for (int fj = 0; fj < 4; ++fj) {                                      \
          const int b_loc = (wid >> 2) * 64 + fj * 16 + llo;                  \
          float v0 = acc[qr][QC][fi][fj][0] + bi.x;                           \
          float v1 = acc[qr][QC][fi][fj][1] + bi.y;                           \
          float v2 = acc[qr][QC][fi][fj][2] + bi.z;                           \
          float v3 = acc[qr][QC][fi][fj][3] + bi.w;                           \
          v0 = v0 > 0.f ? v0 : __expf(v0) - 1.0f;                             \
          v1 = v1 > 0.f ? v1 : __expf(v1) - 1.0f;                             \
          v2 = v2 > 0.f ? v2 : __expf(v2) - 1.0f;                             \
          v3 = v3 > 0.f ? v3 : __expf(v3) - 1.0f;                             \
          ushort4 pk;                                                         \
          pk.x = f2bf(v0); pk.y = f2bf(v1); pk.z = f2bf(v2); pk.w = f2bf(v3); \
          const int byte = (b_loc * 512 + h_loc * 2) ^ ((b_loc & 7) << 4);    \
          *(ushort4*)(lds + byte) = pk;                                       \
        }                                                                     \
      }                                                                       \
    __syncthreads();                                                          \
    _Pragma("unroll")                                                         \
    for (int i = 0; i < 8; ++i) {                                             \
      const int c = i * 512 + t;                                              \
      const int bl = c >> 5, hc = c & 31;                                     \
      const int byte = (bl * 512 + hc * 16) ^ ((bl & 7) << 4);                \
      bf16x8 v = *(const bf16x8*)(lds + byte);                                \
      *(bf16x8*)&Hm[(size_t)(b0 + (QC) * 128 + bl) * 1024 + h0 + hc * 8] = v; \
    }                                                                         \
  } while (0)

__global__ __launch_bounds__(512, 2) void gemm1_kernel(
    const bf16* __restrict__ X,    // [32][1024][512]
    const bf16* __restrict__ W1t,  // [32][1024][512]
    const float* __restrict__ b1,  // [32][1024]
    bf16* __restrict__ Hout) {     // [32][1024][1024]
  extern __shared__ char lds[];

  const int bid = blockIdx.x;
  const int swz = (bid & 7) * 64 + (bid >> 3);   // nwg=512, bijective
  const int m  = swz >> 4;
  const int r_ = swz & 15;
  const int hb = r_ >> 2, bb = r_ & 3;

  const int t = threadIdx.x;
  const int lane = t & 63, wid = t >> 6;
  const int llo = lane & 15, lhi = lane >> 4;

  const bf16* Ag = W1t + (size_t)m * (1024 * 512) + (size_t)(hb * 256) * 512;
  const bf16* Bg = X   + (size_t)m * (1024 * 512) + (size_t)(bb * 256) * 512;

  const f32x4 fzero = {0.f, 0.f, 0.f, 0.f};
  f32x4 acc[2][2][2][4];
#pragma unroll
  for (int a = 0; a < 2; ++a)
#pragma unroll
    for (int b = 0; b < 2; ++b)
#pragma unroll
      for (int c = 0; c < 2; ++c)
#pragma unroll
        for (int d = 0; d < 4; ++d) acc[a][b][c][d] = fzero;

  gemm_core<512, 16>(Ag, Bg, lds, acc, t);

  bf16* Hm = Hout + (size_t)m * (1024 * 1024);
  const float* b1m = b1 + m * 1024 + hb * 256;
  const int b0 = bb * 256, h0 = hb * 256;
  EPI(0);
  EPI(1);
}

// ---------------------------------------------------------------------------
// GEMM2: C[d][b] = W2t[d][:] . H[b][:] (K=1024);
// out[b][inv[b][m]][d] = C + b2 + x via float4 stores.
// 256x256 tile; grid 256 = 32m * 2db * 4bb, XCD-swizzled.
// ---------------------------------------------------------------------------
__global__ __launch_bounds__(512, 2) void gemm2_kernel(
    const bf16* __restrict__ Hin,  // [32][1024][1024]
    const bf16* __restrict__ W2t,  // [32][512][1024]
    const float* __restrict__ b2,  // [32][512]
    const bf16* __restrict__ Xb,   // [32][1024][512]
    const int* __restrict__ inv,   // [1024][32]
    float* __restrict__ out) {     // [1024][32][512]
  extern __shared__ char lds[];

  const int bid = blockIdx.x;
  const int swz = (bid & 7) * 32 + (bid >> 3);   // nwg=256, bijective
  const int m  = swz >> 3;
  const int r_ = swz & 7;
  const int db_ = r_ >> 2, bb = r_ & 3;

  const int t = threadIdx.x;
  const int lane = t & 63, wid = t >> 6;
  const int llo = lane & 15, lhi = lane >> 4;

  const bf16* Ag = W2t + (size_t)m * (512 * 1024) + (size_t)(db_ * 256) * 1024;
  const bf16* Bg = Hin + (size_t)m * (1024 * 1024) + (size_t)(bb * 256) * 1024;

  const f32x4 fzero = {0.f, 0.f, 0.f, 0.f};
  f32x4 acc[2][2][2][4];
#pragma unroll
  for (int a = 0; a < 2; ++a)
#pragma unroll
    for (int b = 0; b < 2; ++b)
#pragma unroll
      for (int c = 0; c < 2; ++c)
#pragma unroll
        for (int d = 0; d < 4; ++d) acc[a][b][c][d] = fzero;

  gemm_core<1024, 32>(Ag, Bg, lds, acc, t);

  const float* b2m = b2 + m * 512;
  const bf16* Xm = Xb + (size_t)m * (1024 * 512);
#pragma unroll
  for (int qc = 0; qc < 2; ++qc)
#pragma unroll
    for (int fj = 0; fj < 4; ++fj) {
      const int b_ = bb * 256 + qc * 128 + (wid >> 2) * 64 + fj * 16 + llo;
      const int n_out = inv[b_ * 32 + m];
      float* orow = out + ((size_t)b_ * 32 + n_out) * 512;
      const bf16* xrow = Xm + (size_t)b_ * 512;
#pragma unroll
      for (int qr = 0; qr < 2; ++qr)
#pragma unroll
        for (int fi = 0; fi < 2; ++fi) {
          const int d0 = db_ * 256 + qr * 128 + (wid & 3) * 32 + fi * 16 + lhi * 4;
          const float4 bi = *(const float4*)&b2m[d0];
          const ushort4 xr = *(const ushort4*)&xrow[d0];
          float4 v;
          v.x = acc[qr][qc][fi][fj][0] + bi.x + bf2f(xr.x);
          v.y = acc[qr][qc][fi][fj][1] + bi.y + bf2f(xr.y);
          v.z = acc[qr][qc][fi][fj][2] + bi.z + bf2f(xr.z);
          v.w = acc[qr][qc][fi][fj][3] + bi.w + bf2f(xr.w);
          *(float4*)&orow[d0] = v;
        }
    }
}

// ---------------------------------------------------------------------------
extern "C" void kernel_launch(void* const* d_in, const int* in_sizes, int n_in,
                              void* d_out, int out_size, void* d_ws, size_t ws_size,
                              hipStream_t stream) {
  const float* z     = (const float*)d_in[0];
  const int*   idx   = (const int*)d_in[1];
  const float* A     = (const float*)d_in[2];
  const float* W1    = (const float*)d_in[3];
  const float* b1    = (const float*)d_in[4];
  const float* W2    = (const float*)d_in[5];
  const float* b2    = (const float*)d_in[6];
  const float* gamma = (const float*)d_in[7];
  const float* beta  = (const float*)d_in[8];
  float* out = (float*)d_out;
  char* ws = (char*)d_ws;

  const size_t OFF_X   = 0;           // bf16 [32][1024][512]  : 32 MiB
  const size_t OFF_H   = 33554432;    // bf16 [32][1024][1024] : 64 MiB
  const size_t OFF_W1T = 100663296;   // bf16 [32][1024][512]  : 32 MiB
  const size_t OFF_W2T = 134217728;   // bf16 [32][512][1024]  : 32 MiB
  const size_t OFF_INV = 167772160;   // int  [1024][32]       : 128 KiB
  const size_t NEED    = 167903232;
  if (ws_size < NEED) return;

  bf16* Xb  = (bf16*)(ws + OFF_X);
  bf16* Hb  = (bf16*)(ws + OFF_H);
  bf16* W1t = (bf16*)(ws + OFF_W1T);
  bf16* W2t = (bf16*)(ws + OFF_W2T);
  int*  inv = (int*)(ws + OFF_INV);

  hipFuncSetAttribute((const void*)gemm1_kernel,
                      hipFuncAttributeMaxDynamicSharedMemorySize, 65536);
  hipFuncSetAttribute((const void*)gemm2_kernel,
                      hipFuncAttributeMaxDynamicSharedMemorySize, 65536);

  // W1 [32][512][1024] -> W1t [32][1024][512]
  transpose_cast_kernel<<<dim3(16, 8, 32), 256, 0, stream>>>(W1, W1t, 512, 1024);
  // W2 [32][1024][512] -> W2t [32][512][1024]
  transpose_cast_kernel<<<dim3(8, 16, 32), 256, 0, stream>>>(W2, W2t, 1024, 512);

  mix_ln_kernel<<<dim3(B_), 256, 0, stream>>>(z, idx, A, gamma, beta, Xb, inv);

  gemm1_kernel<<<dim3(512), 512, 65536, stream>>>(Xb, W1t, b1, Hb);
  gemm2_kernel<<<dim3(256), 512, 65536, stream>>>(Hb, W2t, b2, Xb, inv, out);
}

// Round 15
// 167.271 us; speedup vs baseline: 1.0474x; 1.0474x over previous
//
#include <hip/hip_runtime.h>
#include <hip/hip_bf16.h>
#include <math.h>

// Problem constants
#define B_  1024
#define N_  32
#define D_  512
#define EPS_ 1e-5f

typedef __attribute__((ext_vector_type(8))) short bf16x8;   // 8 bf16 = 4 VGPRs
typedef __attribute__((ext_vector_type(4))) float f32x4;
using bf16 = __hip_bfloat16;
typedef unsigned int u32;
typedef const u32 __attribute__((address_space(1)))* gp_t;
typedef u32 __attribute__((address_space(3)))* sp_t;

// async global->LDS, 16 B per lane, lds dest = wave-uniform base + lane*16
static __device__ __forceinline__ void gload16(const void* g, void* s) {
  __builtin_amdgcn_global_load_lds((gp_t)g, (sp_t)s, 16, 0, 0);
}
static __device__ __forceinline__ void bar() {
  asm volatile("s_barrier" ::: "memory");
}

static __device__ __forceinline__ unsigned short f2bf(float f) {
  union { float f; u32 u; } c; c.f = f;
  u32 r = c.u + 0x7fff + ((c.u >> 16) & 1);   // RNE
  return (unsigned short)(r >> 16);
}
static __device__ __forceinline__ float bf2f(unsigned short h) {
  union { u32 u; float f; } c; c.u = ((u32)h) << 16;
  return c.f;
}

// ---------------------------------------------------------------------------
// Fused prep (r13 config -- measured best total): one dispatch does
// W1 transpose (blocks 0..4095), W2 transpose (4096..8191), mix+LN
// (8192..9215). Bench ground-truth showed fused = 167.2 vs separate 175.2
// (the "88us" rocprof reading was profiler-inflated).
// ---------------------------------------------------------------------------
static __device__ __forceinline__ void transpose_tile(
    const float* __restrict__ in, bf16* __restrict__ out,
    int R, int C, int bx, int by, int bz, int t) {
  __shared__ unsigned short tile[64][65];
  const size_t mat = (size_t)bz * (size_t)R * (size_t)C;
  const float* inp = in + mat;
  bf16* outp = out + mat;
  const int c0 = bx * 64, r0 = by * 64;
  const int tr = t >> 4;           // 0..15
  const int tc = (t & 15) * 4;     // 0,4,..,60
#pragma unroll
  for (int i = 0; i < 4; ++i) {
    const int r = tr + i * 16;
    float4 v = *(const float4*)&inp[(size_t)(r0 + r) * C + c0 + tc];
    tile[r][tc + 0] = f2bf(v.x);
    tile[r][tc + 1] = f2bf(v.y);
    tile[r][tc + 2] = f2bf(v.z);
    tile[r][tc + 3] = f2bf(v.w);
  }
  __syncthreads();
#pragma unroll
  for (int i = 0; i < 2; ++i) {
    const int chunk = i * 256 + t;
    const int c = chunk >> 3, r8 = (chunk & 7) * 8;
    union { bf16x8 v; unsigned short u[8]; } pk;
#pragma unroll
    for (int k = 0; k < 8; ++k) pk.u[k] = tile[r8 + k][c];
    *(bf16x8*)&outp[(size_t)(c0 + c) * R + r0 + r8] = pk.v;
  }
}

static __device__ __forceinline__ void mix_ln_body(
    int b, int t,
    const float* __restrict__ z, const int* __restrict__ idx,
    const float* __restrict__ A, const float* __restrict__ gamma,
    const float* __restrict__ beta, bf16* __restrict__ x_ws,
    int* __restrict__ inv_ws) {
  __shared__ float As[32][32];      // As[k][n] = A[p[k]][n]
  __shared__ int   p[32];
  __shared__ float red1[4][32];
  __shared__ float red2[4][32];
  __shared__ float meanS[32];
  __shared__ float rstdS[32];

  const int lane = t & 63, wid = t >> 6;      // 4 waves
  const int llo = lane & 15, lhi = lane >> 4; // col-lane / row-group

  if (t < 32) {
    int v = idx[b * 32 + t];
    p[t] = v;
    inv_ws[b * 32 + v] = t;
  }
  __syncthreads();
#pragma unroll
  for (int i = 0; i < 4; ++i) {
    const int id = i * 256 + t;
    As[id >> 5][id & 31] = A[p[id >> 5] * 32 + (id & 31)];
  }
  __syncthreads();

  bf16x8 af[2];
#pragma unroll
  for (int nt = 0; nt < 2; ++nt) {
    union { bf16x8 v; unsigned short s[8]; } u;
#pragma unroll
    for (int j = 0; j < 8; ++j)
      u.s[j] = f2bf(As[lhi * 8 + j][nt * 16 + llo]);
    af[nt] = u.v;
  }

  const float* zb = z + (size_t)b * (N_ * D_) + (size_t)(lhi * 8) * D_ + llo;
  const f32x4 fz = {0.f, 0.f, 0.f, 0.f};
  f32x4 acc[2][8];
#pragma unroll
  for (int nt = 0; nt < 2; ++nt)
#pragma unroll
    for (int dt = 0; dt < 8; ++dt) acc[nt][dt] = fz;

#pragma unroll
  for (int h = 0; h < 2; ++h) {
    float zr[4][8];
#pragma unroll
    for (int dd = 0; dd < 4; ++dd)
#pragma unroll
      for (int j = 0; j < 8; ++j)
        zr[dd][j] = zb[j * D_ + ((wid * 8 + h * 4 + dd) * 16)];
#pragma unroll
    for (int dd = 0; dd < 4; ++dd) {
      const int dt = h * 4 + dd;
      union { bf16x8 v; unsigned short s[8]; } u;
#pragma unroll
      for (int j = 0; j < 8; ++j) u.s[j] = f2bf(zr[dd][j]);
      acc[0][dt] = __builtin_amdgcn_mfma_f32_16x16x32_bf16(af[0], u.v, acc[0][dt], 0, 0, 0);
      acc[1][dt] = __builtin_amdgcn_mfma_f32_16x16x32_bf16(af[1], u.v, acc[1][dt], 0, 0, 0);
    }
  }

  float s1[2][4], s2[2][4];
#pragma unroll
  for (int nt = 0; nt < 2; ++nt)
#pragma unroll
    for (int r = 0; r < 4; ++r) {
      float a = 0.f, q = 0.f;
#pragma unroll
      for (int dt = 0; dt < 8; ++dt) {
        float v = acc[nt][dt][r];
        a += v; q += v * v;
      }
#pragma unroll
      for (int mk = 1; mk < 16; mk <<= 1) {
        a += __shfl_xor(a, mk);
        q += __shfl_xor(q, mk);
      }
      s1[nt][r] = a; s2[nt][r] = q;
    }
  if (llo == 0) {
#pragma unroll
    for (int nt = 0; nt < 2; ++nt)
#pragma unroll
      for (int r = 0; r < 4; ++r) {
        const int n = nt * 16 + lhi * 4 + r;
        red1[wid][n] = s1[nt][r];
        red2[wid][n] = s2[nt][r];
      }
  }
  __syncthreads();
  if (t < 32) {
    float S1 = red1[0][t] + red1[1][t] + red1[2][t] + red1[3][t];
    float S2 = red2[0][t] + red2[1][t] + red2[2][t] + red2[3][t];
    float mean = S1 * (1.f / D_);
    float var  = S2 * (1.f / D_) - mean * mean;
    meanS[t] = mean;
    rstdS[t] = rsqrtf(var + EPS_);
  }
  __syncthreads();

  float gv[8], bev[8];
#pragma unroll
  for (int dt = 0; dt < 8; ++dt) {
    const int d = (wid * 8 + dt) * 16 + llo;
    gv[dt] = gamma[d]; bev[dt] = beta[d];
  }
#pragma unroll
  for (int nt = 0; nt < 2; ++nt)
#pragma unroll
    for (int r = 0; r < 4; ++r) {
      const int n = nt * 16 + lhi * 4 + r;
      const float mn = meanS[n], rs = rstdS[n];
      unsigned short* xrow = (unsigned short*)(x_ws + ((size_t)n * B_ + b) * D_);
#pragma unroll
      for (int dt = 0; dt < 8; ++dt) {
        const int d = (wid * 8 + dt) * 16 + llo;
        float v = (acc[nt][dt][r] - mn) * rs * gv[dt] + bev[dt];
        xrow[d] = f2bf(v);
      }
    }
}

__global__ __launch_bounds__(256) void prep_kernel(
    const float* __restrict__ W1, const float* __restrict__ W2,
    bf16* __restrict__ W1t, bf16* __restrict__ W2t,
    const float* __restrict__ z, const int* __restrict__ idx,
    const float* __restrict__ A, const float* __restrict__ gamma,
    const float* __restrict__ beta, bf16* __restrict__ x_ws,
    int* __restrict__ inv_ws) {
  const int bid = blockIdx.x;
  const int t = threadIdx.x;
  if (bid < 4096) {
    // W1 [32][512][1024] -> W1t [32][1024][512]
    transpose_tile(W1, W1t, 512, 1024, bid & 15, (bid >> 4) & 7, bid >> 7, t);
  } else if (bid < 8192) {
    // W2 [32][1024][512] -> W2t [32][512][1024]
    const int b2 = bid - 4096;
    transpose_tile(W2, W2t, 1024, 512, b2 & 7, (b2 >> 3) & 15, b2 >> 7, t);
  } else {
    mix_ln_body(bid - 8192, t, z, idx, A, gamma, beta, x_ws, inv_ws);
  }
}

// ---------------------------------------------------------------------------
// 256x256 GEMM core, BK=32, 8 waves, 64KB LDS, FAT fragment set (the
// information-minimum 12 b128/subtile: av[2] + bv0[4] + bv1[4] all held;
// A reloaded once mid-subtile). launch_bounds(512,2) -- NO forced VGPR cap
// (the r11/r12 (512,4) cap forced acc into scratch: 4-6x regression). r8's
// identical live set compiled to exactly 128 naturally; <=128 here + 64KB
// LDS -> 2 blocks/CU with minimum LDS traffic.
// BK=32 rows = 64B: ds_read_b128 near bank-floor (measured ~4.6/instr).
// LDS: A parity p at p*16K (halves 8K = 128 rows); B at 32K + p*16K.
// Per subtile: 12 b128 reads, 32 MFMA (setprio), bar, stage s+2 (4 gload16),
// counted vmcnt(4), bar. Lookahead 2 subtiles (>= HBM latency).
// ---------------------------------------------------------------------------
#define STGA(P, H, S)                                                         \
  gload16(Ag + (size_t)((H) * 128) * KD + (S) * 32 + soff,                    \
          lds + (P) * 16384 + (H) * 8192 + dof)
#define STGB(P, H, S)                                                         \
  gload16(Bg + (size_t)((H) * 128) * KD + (S) * 32 + soff,                    \
          lds + 32768 + (P) * 16384 + (H) * 8192 + dof)

#define RDA(P, H, AV) do {                                                    \
    const char* a_ = lds + (P) * 16384 + (H) * 8192;                          \
    AV[0] = *(const bf16x8*)(a_ + (widA * 32 + llo) * 64 + k16);              \
    AV[1] = *(const bf16x8*)(a_ + (widA * 32 + 16 + llo) * 64 + k16);         \
  } while (0)
#define RDB(P, H, BV) do {                                                    \
    const char* b_ = lds + 32768 + (P) * 16384 + (H) * 8192;                  \
    _Pragma("unroll")                                                         \
    for (int fj = 0; fj < 4; ++fj)                                            \
      BV[fj] = *(const bf16x8*)(b_ + (widB * 64 + fj * 16 + llo) * 64 + k16); \
  } while (0)

#define MMA8(QR, QC, AV, BV) do {                                             \
    __builtin_amdgcn_s_setprio(1);                                            \
    _Pragma("unroll")                                                         \
    for (int fi = 0; fi < 2; ++fi)                                            \
      _Pragma("unroll")                                                       \
      for (int fj = 0; fj < 4; ++fj)                                          \
        acc[QR][QC][fi][fj] = __builtin_amdgcn_mfma_f32_16x16x32_bf16(        \
            AV[fi], BV[fj], acc[QR][QC][fi][fj], 0, 0, 0);                    \
    __builtin_amdgcn_s_setprio(0);                                            \
  } while (0)

#define VMC4() asm volatile("s_waitcnt vmcnt(4)" ::: "memory")
#define VMC0() asm volatile("s_waitcnt vmcnt(0)" ::: "memory")

#define SUBTILE(P, S) do {                                                    \
    bf16x8 av[2], bv0[4], bv1[4];                                             \
    RDA(P, 0, av); RDB(P, 0, bv0); RDB(P, 1, bv1);                            \
    MMA8(0, 0, av, bv0);                                                      \
    MMA8(0, 1, av, bv1);                                                      \
    RDA(P, 1, av);                                                            \
    MMA8(1, 0, av, bv0);                                                      \
    MMA8(1, 1, av, bv1);                                                      \
    bar();                                   /* all waves consumed buffer P */\
    if ((S) + 2 < NS) {                                                       \
      STGA(P, 0, (S) + 2); STGA(P, 1, (S) + 2);                               \
      STGB(P, 0, (S) + 2); STGB(P, 1, (S) + 2);                               \
      VMC4();                                /* retire subtile S+1's units */ \
    } else { VMC0(); }                                                        \
    bar();                                   /* buffer P^1 (S+1) published */ \
  } while (0)

template <int KD, int NS>
static __device__ __forceinline__ void gemm_core(
    const bf16* __restrict__ Ag, const bf16* __restrict__ Bg,
    char* __restrict__ lds, f32x4 (&acc)[2][2][2][4], const int t) {
  const int lane = t & 63, wid = t >> 6;
  const int llo = lane & 15, lhi = lane >> 4;
  const int widA = wid & 3, widB = wid >> 2;
  const int k16 = lhi * 16;                            // k-slot byte offset
  const size_t soff = (size_t)(t >> 2) * KD + (t & 3) * 8;   // stage src (elems)
  const int dof = wid * 1024;                          // stage LDS dest (bytes)

  // prologue: stage subtiles 0 and 1 fully; wait for subtile 0
  STGA(0, 0, 0); STGA(0, 1, 0); STGB(0, 0, 0); STGB(0, 1, 0);
  STGA(1, 0, 1); STGA(1, 1, 1); STGB(1, 0, 1); STGB(1, 1, 1);
  VMC4();
  bar();

#pragma unroll 1
  for (int it = 0; it < NS / 2; ++it) {
    SUBTILE(0, 2 * it);
    SUBTILE(1, 2 * it + 1);
  }
}

// ---------------------------------------------------------------------------
// GEMM1: C[h][b] = W1t[h][:] . X[b][:] (K=512), bias+ELU -> H[b][h] bf16.
// 256x256 tile; epilogue via LDS in two compile-time 64KB passes.
// grid 512 = 32m*4hb*4bb, XCD-swizzled.
// ---------------------------------------------------------------------------
#define EPI(QC) do {                                                          \
    __syncthreads();                                                          \
    _Pragma("unroll")                                                         \
    for (int qr = 0; qr < 2; ++qr)                                            \
      _Pragma("unroll")                                                       \
      for (int fi = 0; fi < 2; ++fi) {                                        \
        const int h_loc = qr * 128 + (wid & 3) * 32 + fi * 16 + lhi * 4;      \
        const float4 bi = *(const float4*)&b1m[h_loc];                        \
        _Pragma("unroll")                                                     \
        for (int fj = 0; fj < 4; ++fj) {                                      \
          const int b_loc = (wid >> 2) * 64 + fj * 16 + llo;                  \
          float v0 = acc[qr][QC][fi][fj][0] + bi.x;                           \
          float v1 = acc[qr][QC][fi][fj][1] + bi.y;                           \
          float v2 = acc[qr][QC][fi][fj][2] + bi.z;                           \
          float v3 = acc[qr][QC][fi][fj][3] + bi.w;                           \
          v0 = v0 > 0.f ? v0 : __expf(v0) - 1.0f;                             \
          v1 = v1 > 0.f ? v1 : __expf(v1) - 1.0f;                             \
          v2 = v2 > 0.f ? v2 : __expf(v2) - 1.0f;                             \
          v3 = v3 > 0.f ? v3 : __expf(v3) - 1.0f;                             \
          ushort4 pk;                                                         \
          pk.x = f2bf(v0); pk.y = f2bf(v1); pk.z = f2bf(v2); pk.w = f2bf(v3); \
          const int byte = (b_loc * 512 + h_loc * 2) ^ ((b_loc & 7) << 4);    \
          *(ushort4*)(lds + byte) = pk;                                       \
        }                                                                     \
      }                                                                       \
    __syncthreads();                                                          \
    _Pragma("unroll")                                                         \
    for (int i = 0; i < 8; ++i) {                                             \
      const int c = i * 512 + t;                                              \
      const int bl = c >> 5, hc = c & 31;                                     \
      const int byte = (bl * 512 + hc * 16) ^ ((bl & 7) << 4);                \
      bf16x8 v = *(const bf16x8*)(lds + byte);                                \
      *(bf16x8*)&Hm[(size_t)(b0 + (QC) * 128 + bl) * 1024 + h0 + hc * 8] = v; \
    }                                                                         \
  } while (0)

__global__ __launch_bounds__(512, 2) void gemm1_kernel(
    const bf16* __restrict__ X,    // [32][1024][512]
    const bf16* __restrict__ W1t,  // [32][1024][512]
    const float* __restrict__ b1,  // [32][1024]
    bf16* __restrict__ Hout) {     // [32][1024][1024]
  extern __shared__ char lds[];

  const int bid = blockIdx.x;
  const int swz = (bid & 7) * 64 + (bid >> 3);   // nwg=512, bijective
  const int m  = swz >> 4;
  const int r_ = swz & 15;
  const int hb = r_ >> 2, bb = r_ & 3;

  const int t = threadIdx.x;
  const int lane = t & 63, wid = t >> 6;
  const int llo = lane & 15, lhi = lane >> 4;

  const bf16* Ag = W1t + (size_t)m * (1024 * 512) + (size_t)(hb * 256) * 512;
  const bf16* Bg = X   + (size_t)m * (1024 * 512) + (size_t)(bb * 256) * 512;

  const f32x4 fzero = {0.f, 0.f, 0.f, 0.f};
  f32x4 acc[2][2][2][4];
#pragma unroll
  for (int a = 0; a < 2; ++a)
#pragma unroll
    for (int b = 0; b < 2; ++b)
#pragma unroll
      for (int c = 0; c < 2; ++c)
#pragma unroll
        for (int d = 0; d < 4; ++d) acc[a][b][c][d] = fzero;

  gemm_core<512, 16>(Ag, Bg, lds, acc, t);

  bf16* Hm = Hout + (size_t)m * (1024 * 1024);
  const float* b1m = b1 + m * 1024 + hb * 256;
  const int b0 = bb * 256, h0 = hb * 256;
  EPI(0);
  EPI(1);
}

// ---------------------------------------------------------------------------
// GEMM2: C[d][b] = W2t[d][:] . H[b][:] (K=1024);
// out[b][inv[b][m]][d] = C + b2 + x via float4 stores.
// 256x256 tile; grid 256 = 32m * 2db * 4bb, XCD-swizzled.
// ---------------------------------------------------------------------------
__global__ __launch_bounds__(512, 2) void gemm2_kernel(
    const bf16* __restrict__ Hin,  // [32][1024][1024]
    const bf16* __restrict__ W2t,  // [32][512][1024]
    const float* __restrict__ b2,  // [32][512]
    const bf16* __restrict__ Xb,   // [32][1024][512]
    const int* __restrict__ inv,   // [1024][32]
    float* __restrict__ out) {     // [1024][32][512]
  extern __shared__ char lds[];

  const int bid = blockIdx.x;
  const int swz = (bid & 7) * 32 + (bid >> 3);   // nwg=256, bijective
  const int m  = swz >> 3;
  const int r_ = swz & 7;
  const int db_ = r_ >> 2, bb = r_ & 3;

  const int t = threadIdx.x;
  const int lane = t & 63, wid = t >> 6;
  const int llo = lane & 15, lhi = lane >> 4;

  const bf16* Ag = W2t + (size_t)m * (512 * 1024) + (size_t)(db_ * 256) * 1024;
  const bf16* Bg = Hin + (size_t)m * (1024 * 1024) + (size_t)(bb * 256) * 1024;

  const f32x4 fzero = {0.f, 0.f, 0.f, 0.f};
  f32x4 acc[2][2][2][4];
#pragma unroll
  for (int a = 0; a < 2; ++a)
#pragma unroll
    for (int b = 0; b < 2; ++b)
#pragma unroll
      for (int c = 0; c < 2; ++c)
#pragma unroll
        for (int d = 0; d < 4; ++d) acc[a][b][c][d] = fzero;

  gemm_core<1024, 32>(Ag, Bg, lds, acc, t);

  const float* b2m = b2 + m * 512;
  const bf16* Xm = Xb + (size_t)m * (1024 * 512);
#pragma unroll
  for (int qc = 0; qc < 2; ++qc)
#pragma unroll
    for (int fj = 0; fj < 4; ++fj) {
      const int b_ = bb * 256 + qc * 128 + (wid >> 2) * 64 + fj * 16 + llo;
      const int n_out = inv[b_ * 32 + m];
      float* orow = out + ((size_t)b_ * 32 + n_out) * 512;
      const bf16* xrow = Xm + (size_t)b_ * 512;
#pragma unroll
      for (int qr = 0; qr < 2; ++qr)
#pragma unroll
        for (int fi = 0; fi < 2; ++fi) {
          const int d0 = db_ * 256 + qr * 128 + (wid & 3) * 32 + fi * 16 + lhi * 4;
          const float4 bi = *(const float4*)&b2m[d0];
          const ushort4 xr = *(const ushort4*)&xrow[d0];
          float4 v;
          v.x = acc[qr][qc][fi][fj][0] + bi.x + bf2f(xr.x);
          v.y = acc[qr][qc][fi][fj][1] + bi.y + bf2f(xr.y);
          v.z = acc[qr][qc][fi][fj][2] + bi.z + bf2f(xr.z);
          v.w = acc[qr][qc][fi][fj][3] + bi.w + bf2f(xr.w);
          *(float4*)&orow[d0] = v;
        }
    }
}

// ---------------------------------------------------------------------------
extern "C" void kernel_launch(void* const* d_in, const int* in_sizes, int n_in,
                              void* d_out, int out_size, void* d_ws, size_t ws_size,
                              hipStream_t stream) {
  const float* z     = (const float*)d_in[0];
  const int*   idx   = (const int*)d_in[1];
  const float* A     = (const float*)d_in[2];
  const float* W1    = (const float*)d_in[3];
  const float* b1    = (const float*)d_in[4];
  const float* W2    = (const float*)d_in[5];
  const float* b2    = (const float*)d_in[6];
  const float* gamma = (const float*)d_in[7];
  const float* beta  = (const float*)d_in[8];
  float* out = (float*)d_out;
  char* ws = (char*)d_ws;

  const size_t OFF_X   = 0;           // bf16 [32][1024][512]  : 32 MiB
  const size_t OFF_H   = 33554432;    // bf16 [32][1024][1024] : 64 MiB
  const size_t OFF_W1T = 100663296;   // bf16 [32][1024][512]  : 32 MiB
  const size_t OFF_W2T = 134217728;   // bf16 [32][512][1024]  : 32 MiB
  const size_t OFF_INV = 167772160;   // int  [1024][32]       : 128 KiB
  const size_t NEED    = 167903232;
  if (ws_size < NEED) return;

  bf16* Xb  = (bf16*)(ws + OFF_X);
  bf16* Hb  = (bf16*)(ws + OFF_H);
  bf16* W1t = (bf16*)(ws + OFF_W1T);
  bf16* W2t = (bf16*)(ws + OFF_W2T);
  int*  inv = (int*)(ws + OFF_INV);

  hipFuncSetAttribute((const void*)gemm1_kernel,
                      hipFuncAttributeMaxDynamicSharedMemorySize, 65536);
  hipFuncSetAttribute((const void*)gemm2_kernel,
                      hipFuncAttributeMaxDynamicSharedMemorySize, 65536);

  // fused prep: W1t + W2t transposes and mix+LN in one dispatch
  prep_kernel<<<dim3(9216), 256, 0, stream>>>(W1, W2, W1t, W2t,
                                              z, idx, A, gamma, beta, Xb, inv);

  gemm1_kernel<<<dim3(512), 512, 65536, stream>>>(Xb, W1t, b1, Hb);
  gemm2_kernel<<<dim3(256), 512, 65536, stream>>>(Hb, W2t, b2, Xb, inv, out);
}

// Round 16
// 164.284 us; speedup vs baseline: 1.0665x; 1.0182x over previous
//
#include <hip/hip_runtime.h>
#include <hip/hip_bf16.h>
#include <math.h>

// Problem constants
#define B_  1024
#define N_  32
#define D_  512
#define EPS_ 1e-5f

typedef __attribute__((ext_vector_type(8))) short bf16x8;   // 8 bf16 = 4 VGPRs
typedef __attribute__((ext_vector_type(4))) float f32x4;
using bf16 = __hip_bfloat16;
typedef unsigned int u32;
typedef const u32 __attribute__((address_space(1)))* gp_t;
typedef u32 __attribute__((address_space(3)))* sp_t;

// async global->LDS, 16 B per lane, lds dest = wave-uniform base + lane*16
static __device__ __forceinline__ void gload16(const void* g, void* s) {
  __builtin_amdgcn_global_load_lds((gp_t)g, (sp_t)s, 16, 0, 0);
}
static __device__ __forceinline__ void bar() {
  asm volatile("s_barrier" ::: "memory");
}

static __device__ __forceinline__ unsigned short f2bf(float f) {
  union { float f; u32 u; } c; c.f = f;
  u32 r = c.u + 0x7fff + ((c.u >> 16) & 1);   // RNE
  return (unsigned short)(r >> 16);
}
static __device__ __forceinline__ float bf2f(unsigned short h) {
  union { u32 u; float f; } c; c.u = ((u32)h) << 16;
  return c.f;
}

// ---------------------------------------------------------------------------
// Fused prep (measured best: fused 167.2 vs separate 175.2): one dispatch
// does W1 transpose (blocks 0..4095), W2 transpose (4096..8191), mix+LN
// (8192..9215). Prep is ~50us vs 46us HBM floor -- done.
// ---------------------------------------------------------------------------
static __device__ __forceinline__ void transpose_tile(
    const float* __restrict__ in, bf16* __restrict__ out,
    int R, int C, int bx, int by, int bz, int t) {
  __shared__ unsigned short tile[64][65];
  const size_t mat = (size_t)bz * (size_t)R * (size_t)C;
  const float* inp = in + mat;
  bf16* outp = out + mat;
  const int c0 = bx * 64, r0 = by * 64;
  const int tr = t >> 4;           // 0..15
  const int tc = (t & 15) * 4;     // 0,4,..,60
#pragma unroll
  for (int i = 0; i < 4; ++i) {
    const int r = tr + i * 16;
    float4 v = *(const float4*)&inp[(size_t)(r0 + r) * C + c0 + tc];
    tile[r][tc + 0] = f2bf(v.x);
    tile[r][tc + 1] = f2bf(v.y);
    tile[r][tc + 2] = f2bf(v.z);
    tile[r][tc + 3] = f2bf(v.w);
  }
  __syncthreads();
#pragma unroll
  for (int i = 0; i < 2; ++i) {
    const int chunk = i * 256 + t;
    const int c = chunk >> 3, r8 = (chunk & 7) * 8;
    union { bf16x8 v; unsigned short u[8]; } pk;
#pragma unroll
    for (int k = 0; k < 8; ++k) pk.u[k] = tile[r8 + k][c];
    *(bf16x8*)&outp[(size_t)(c0 + c) * R + r0 + r8] = pk.v;
  }
}

static __device__ __forceinline__ void mix_ln_body(
    int b, int t,
    const float* __restrict__ z, const int* __restrict__ idx,
    const float* __restrict__ A, const float* __restrict__ gamma,
    const float* __restrict__ beta, bf16* __restrict__ x_ws,
    int* __restrict__ inv_ws) {
  __shared__ float As[32][32];      // As[k][n] = A[p[k]][n]
  __shared__ int   p[32];
  __shared__ float red1[4][32];
  __shared__ float red2[4][32];
  __shared__ float meanS[32];
  __shared__ float rstdS[32];

  const int lane = t & 63, wid = t >> 6;      // 4 waves
  const int llo = lane & 15, lhi = lane >> 4; // col-lane / row-group

  if (t < 32) {
    int v = idx[b * 32 + t];
    p[t] = v;
    inv_ws[b * 32 + v] = t;
  }
  __syncthreads();
#pragma unroll
  for (int i = 0; i < 4; ++i) {
    const int id = i * 256 + t;
    As[id >> 5][id & 31] = A[p[id >> 5] * 32 + (id & 31)];
  }
  __syncthreads();

  bf16x8 af[2];
#pragma unroll
  for (int nt = 0; nt < 2; ++nt) {
    union { bf16x8 v; unsigned short s[8]; } u;
#pragma unroll
    for (int j = 0; j < 8; ++j)
      u.s[j] = f2bf(As[lhi * 8 + j][nt * 16 + llo]);
    af[nt] = u.v;
  }

  const float* zb = z + (size_t)b * (N_ * D_) + (size_t)(lhi * 8) * D_ + llo;
  const f32x4 fz = {0.f, 0.f, 0.f, 0.f};
  f32x4 acc[2][8];
#pragma unroll
  for (int nt = 0; nt < 2; ++nt)
#pragma unroll
    for (int dt = 0; dt < 8; ++dt) acc[nt][dt] = fz;

#pragma unroll
  for (int h = 0; h < 2; ++h) {
    float zr[4][8];
#pragma unroll
    for (int dd = 0; dd < 4; ++dd)
#pragma unroll
      for (int j = 0; j < 8; ++j)
        zr[dd][j] = zb[j * D_ + ((wid * 8 + h * 4 + dd) * 16)];
#pragma unroll
    for (int dd = 0; dd < 4; ++dd) {
      const int dt = h * 4 + dd;
      union { bf16x8 v; unsigned short s[8]; } u;
#pragma unroll
      for (int j = 0; j < 8; ++j) u.s[j] = f2bf(zr[dd][j]);
      acc[0][dt] = __builtin_amdgcn_mfma_f32_16x16x32_bf16(af[0], u.v, acc[0][dt], 0, 0, 0);
      acc[1][dt] = __builtin_amdgcn_mfma_f32_16x16x32_bf16(af[1], u.v, acc[1][dt], 0, 0, 0);
    }
  }

  float s1[2][4], s2[2][4];
#pragma unroll
  for (int nt = 0; nt < 2; ++nt)
#pragma unroll
    for (int r = 0; r < 4; ++r) {
      float a = 0.f, q = 0.f;
#pragma unroll
      for (int dt = 0; dt < 8; ++dt) {
        float v = acc[nt][dt][r];
        a += v; q += v * v;
      }
#pragma unroll
      for (int mk = 1; mk < 16; mk <<= 1) {
        a += __shfl_xor(a, mk);
        q += __shfl_xor(q, mk);
      }
      s1[nt][r] = a; s2[nt][r] = q;
    }
  if (llo == 0) {
#pragma unroll
    for (int nt = 0; nt < 2; ++nt)
#pragma unroll
      for (int r = 0; r < 4; ++r) {
        const int n = nt * 16 + lhi * 4 + r;
        red1[wid][n] = s1[nt][r];
        red2[wid][n] = s2[nt][r];
      }
  }
  __syncthreads();
  if (t < 32) {
    float S1 = red1[0][t] + red1[1][t] + red1[2][t] + red1[3][t];
    float S2 = red2[0][t] + red2[1][t] + red2[2][t] + red2[3][t];
    float mean = S1 * (1.f / D_);
    float var  = S2 * (1.f / D_) - mean * mean;
    meanS[t] = mean;
    rstdS[t] = rsqrtf(var + EPS_);
  }
  __syncthreads();

  float gv[8], bev[8];
#pragma unroll
  for (int dt = 0; dt < 8; ++dt) {
    const int d = (wid * 8 + dt) * 16 + llo;
    gv[dt] = gamma[d]; bev[dt] = beta[d];
  }
#pragma unroll
  for (int nt = 0; nt < 2; ++nt)
#pragma unroll
    for (int r = 0; r < 4; ++r) {
      const int n = nt * 16 + lhi * 4 + r;
      const float mn = meanS[n], rs = rstdS[n];
      unsigned short* xrow = (unsigned short*)(x_ws + ((size_t)n * B_ + b) * D_);
#pragma unroll
      for (int dt = 0; dt < 8; ++dt) {
        const int d = (wid * 8 + dt) * 16 + llo;
        float v = (acc[nt][dt][r] - mn) * rs * gv[dt] + bev[dt];
        xrow[d] = f2bf(v);
      }
    }
}

__global__ __launch_bounds__(256) void prep_kernel(
    const float* __restrict__ W1, const float* __restrict__ W2,
    bf16* __restrict__ W1t, bf16* __restrict__ W2t,
    const float* __restrict__ z, const int* __restrict__ idx,
    const float* __restrict__ A, const float* __restrict__ gamma,
    const float* __restrict__ beta, bf16* __restrict__ x_ws,
    int* __restrict__ inv_ws) {
  const int bid = blockIdx.x;
  const int t = threadIdx.x;
  if (bid < 4096) {
    // W1 [32][512][1024] -> W1t [32][1024][512]
    transpose_tile(W1, W1t, 512, 1024, bid & 15, (bid >> 4) & 7, bid >> 7, t);
  } else if (bid < 8192) {
    // W2 [32][1024][512] -> W2t [32][512][1024]
    const int b2 = bid - 4096;
    transpose_tile(W2, W2t, 1024, 512, b2 & 7, (b2 >> 3) & 15, b2 >> 7, t);
  } else {
    mix_ln_body(bid - 8192, t, z, idx, A, gamma, beta, x_ws, inv_ws);
  }
}

// ---------------------------------------------------------------------------
// 256x256 GEMM core, BK=32, 8 waves, 64KB LDS, fat fragments (12 b128 =
// information minimum), SINGLE barrier per subtile (T3 minimum 2-phase):
//   { RD(P); 32 MFMA; vmcnt(0); bar; STG(P, s+2) }
// vmcnt(0) retires subtile s+1's loads -- issued one full subtile (~4000cy)
// earlier, so nearly free; bar simultaneously publishes s+1 to all waves AND
// certifies all waves finished reading P before it's overwritten. Halves the
// barrier count vs r13-r15 (which measured stall-bound: ~22% MfmaUtil with
// ~25% HBM -- neither pipe saturated).
// BK=32 rows = 64B: ds_read_b128 naturally bank-uniform, no swizzle.
// LDS: A parity p at p*16K (halves 8K = 128 rows); B at 32K + p*16K.
// ---------------------------------------------------------------------------
#define STGA(P, H, S)                                                         \
  gload16(Ag + (size_t)((H) * 128) * KD + (S) * 32 + soff,                    \
          lds + (P) * 16384 + (H) * 8192 + dof)
#define STGB(P, H, S)                                                         \
  gload16(Bg + (size_t)((H) * 128) * KD + (S) * 32 + soff,                    \
          lds + 32768 + (P) * 16384 + (H) * 8192 + dof)

#define RDA(P, H, AV) do {                                                    \
    const char* a_ = lds + (P) * 16384 + (H) * 8192;                          \
    AV[0] = *(const bf16x8*)(a_ + (widA * 32 + llo) * 64 + k16);              \
    AV[1] = *(const bf16x8*)(a_ + (widA * 32 + 16 + llo) * 64 + k16);         \
  } while (0)
#define RDB(P, H, BV) do {                                                    \
    const char* b_ = lds + 32768 + (P) * 16384 + (H) * 8192;                  \
    _Pragma("unroll")                                                         \
    for (int fj = 0; fj < 4; ++fj)                                            \
      BV[fj] = *(const bf16x8*)(b_ + (widB * 64 + fj * 16 + llo) * 64 + k16); \
  } while (0)

#define MMA8(QR, QC, AV, BV) do {                                             \
    __builtin_amdgcn_s_setprio(1);                                            \
    _Pragma("unroll")                                                         \
    for (int fi = 0; fi < 2; ++fi)                                            \
      _Pragma("unroll")                                                       \
      for (int fj = 0; fj < 4; ++fj)                                          \
        acc[QR][QC][fi][fj] = __builtin_amdgcn_mfma_f32_16x16x32_bf16(        \
            AV[fi], BV[fj], acc[QR][QC][fi][fj], 0, 0, 0);                    \
    __builtin_amdgcn_s_setprio(0);                                            \
  } while (0)

#define VMC0() asm volatile("s_waitcnt vmcnt(0)" ::: "memory")

// 1-barrier subtile. Hazards: RAW -- buffer P^1 (subtile s+1) was staged at
// s-1's STG; this subtile's VMC0 drains it and bar publishes it before s+1's
// reads. WAR -- STG into P is after bar, by which all waves finished RD(P).
#define SUBTILE(P, S) do {                                                    \
    bf16x8 av[2], bv0[4], bv1[4];                                             \
    RDA(P, 0, av); RDB(P, 0, bv0); RDB(P, 1, bv1);                            \
    MMA8(0, 0, av, bv0);                                                      \
    MMA8(0, 1, av, bv1);                                                      \
    RDA(P, 1, av);                                                            \
    MMA8(1, 0, av, bv0);                                                      \
    MMA8(1, 1, av, bv1);                                                      \
    VMC0();                                 /* s+1's loads (1 subtile old) */ \
    bar();                                  /* publish s+1; reads of P done */\
    if ((S) + 2 < NS) {                                                       \
      STGA(P, 0, (S) + 2); STGA(P, 1, (S) + 2);                               \
      STGB(P, 0, (S) + 2); STGB(P, 1, (S) + 2);                               \
    }                                                                         \
  } while (0)

template <int KD, int NS>
static __device__ __forceinline__ void gemm_core(
    const bf16* __restrict__ Ag, const bf16* __restrict__ Bg,
    char* __restrict__ lds, f32x4 (&acc)[2][2][2][4], const int t) {
  const int lane = t & 63, wid = t >> 6;
  const int llo = lane & 15, lhi = lane >> 4;
  const int widA = wid & 3, widB = wid >> 2;
  const int k16 = lhi * 16;                            // k-slot byte offset
  const size_t soff = (size_t)(t >> 2) * KD + (t & 3) * 8;   // stage src (elems)
  const int dof = wid * 1024;                          // stage LDS dest (bytes)

  // prologue: stage subtiles 0 and 1 fully; drain; publish
  STGA(0, 0, 0); STGA(0, 1, 0); STGB(0, 0, 0); STGB(0, 1, 0);
  STGA(1, 0, 1); STGA(1, 1, 1); STGB(1, 0, 1); STGB(1, 1, 1);
  VMC0();
  bar();

#pragma unroll 1
  for (int it = 0; it < NS / 2; ++it) {
    SUBTILE(0, 2 * it);
    SUBTILE(1, 2 * it + 1);
  }
}

// ---------------------------------------------------------------------------
// GEMM1: C[h][b] = W1t[h][:] . X[b][:] (K=512), bias+ELU -> H[b][h] bf16.
// 256x256 tile; epilogue via LDS in two compile-time 64KB passes.
// grid 512 = 32m*4hb*4bb, XCD-swizzled.
// ---------------------------------------------------------------------------
#define EPI(QC) do {                                                          \
    __syncthreads();                                                          \
    _Pragma("unroll")                                                         \
    for (int qr = 0; qr < 2; ++qr)                                            \
      _Pragma("unroll")                                                       \
      for (int fi = 0; fi < 2; ++fi) {                                        \
        const int h_loc = qr * 128 + (wid & 3) * 32 + fi * 16 + lhi * 4;      \
        const float4 bi = *(const float4*)&b1m[h_loc];                        \
        _Pragma("unroll")                                                     \
        for (int fj = 0; fj < 4; ++fj) {                                      \
          const int b_loc = (wid >> 2) * 64 + fj * 16 + llo;                  \
          float v0 = acc[qr][QC][fi][fj][0] + bi.x;                           \
          float v1 = acc[qr][QC][fi][fj][1] + bi.y;                           \
          float v2 = acc[qr][QC][fi][fj][2] + bi.z;                           \
          float v3 = acc[qr][QC][fi][fj][3] + bi.w;                           \
          v0 = v0 > 0.f ? v0 : __expf(v0) - 1.0f;                             \
          v1 = v1 > 0.f ? v1 : __expf(v1) - 1.0f;                             \
          v2 = v2 > 0.f ? v2 : __expf(v2) - 1.0f;                             \
          v3 = v3 > 0.f ? v3 : __expf(v3) - 1.0f;                             \
          ushort4 pk;                                                         \
          pk.x = f2bf(v0); pk.y = f2bf(v1); pk.z = f2bf(v2); pk.w = f2bf(v3); \
          const int byte = (b_loc * 512 + h_loc * 2) ^ ((b_loc & 7) << 4);    \
          *(ushort4*)(lds + byte) = pk;                                       \
        }                                                                     \
      }                                                                       \
    __syncthreads();                                                          \
    _Pragma("unroll")                                                         \
    for (int i = 0; i < 8; ++i) {                                             \
      const int c = i * 512 + t;                                              \
      const int bl = c >> 5, hc = c & 31;                                     \
      const int byte = (bl * 512 + hc * 16) ^ ((bl & 7) << 4);                \
      bf16x8 v = *(const bf16x8*)(lds + byte);                                \
      *(bf16x8*)&Hm[(size_t)(b0 + (QC) * 128 + bl) * 1024 + h0 + hc * 8] = v; \
    }                                                                         \
  } while (0)

__global__ __launch_bounds__(512, 2) void gemm1_kernel(
    const bf16* __restrict__ X,    // [32][1024][512]
    const bf16* __restrict__ W1t,  // [32][1024][512]
    const float* __restrict__ b1,  // [32][1024]
    bf16* __restrict__ Hout) {     // [32][1024][1024]
  extern __shared__ char lds[];

  const int bid = blockIdx.x;
  const int swz = (bid & 7) * 64 + (bid >> 3);   // nwg=512, bijective
  const int m  = swz >> 4;
  const int r_ = swz & 15;
  const int hb = r_ >> 2, bb = r_ & 3;

  const int t = threadIdx.x;
  const int lane = t & 63, wid = t >> 6;
  const int llo = lane & 15, lhi = lane >> 4;

  const bf16* Ag = W1t + (size_t)m * (1024 * 512) + (size_t)(hb * 256) * 512;
  const bf16* Bg = X   + (size_t)m * (1024 * 512) + (size_t)(bb * 256) * 512;

  const f32x4 fzero = {0.f, 0.f, 0.f, 0.f};
  f32x4 acc[2][2][2][4];
#pragma unroll
  for (int a = 0; a < 2; ++a)
#pragma unroll
    for (int b = 0; b < 2; ++b)
#pragma unroll
      for (int c = 0; c < 2; ++c)
#pragma unroll
        for (int d = 0; d < 4; ++d) acc[a][b][c][d] = fzero;

  gemm_core<512, 16>(Ag, Bg, lds, acc, t);

  bf16* Hm = Hout + (size_t)m * (1024 * 1024);
  const float* b1m = b1 + m * 1024 + hb * 256;
  const int b0 = bb * 256, h0 = hb * 256;
  EPI(0);
  EPI(1);
}

// ---------------------------------------------------------------------------
// GEMM2: C[d][b] = W2t[d][:] . H[b][:] (K=1024);
// out[b][inv[b][m]][d] = C + b2 + x via float4 stores.
// 256x256 tile; grid 256 = 32m * 2db * 4bb, XCD-swizzled.
// ---------------------------------------------------------------------------
__global__ __launch_bounds__(512, 2) void gemm2_kernel(
    const bf16* __restrict__ Hin,  // [32][1024][1024]
    const bf16* __restrict__ W2t,  // [32][512][1024]
    const float* __restrict__ b2,  // [32][512]
    const bf16* __restrict__ Xb,   // [32][1024][512]
    const int* __restrict__ inv,   // [1024][32]
    float* __restrict__ out) {     // [1024][32][512]
  extern __shared__ char lds[];

  const int bid = blockIdx.x;
  const int swz = (bid & 7) * 32 + (bid >> 3);   // nwg=256, bijective
  const int m  = swz >> 3;
  const int r_ = swz & 7;
  const int db_ = r_ >> 2, bb = r_ & 3;

  const int t = threadIdx.x;
  const int lane = t & 63, wid = t >> 6;
  const int llo = lane & 15, lhi = lane >> 4;

  const bf16* Ag = W2t + (size_t)m * (512 * 1024) + (size_t)(db_ * 256) * 1024;
  const bf16* Bg = Hin + (size_t)m * (1024 * 1024) + (size_t)(bb * 256) * 1024;

  const f32x4 fzero = {0.f, 0.f, 0.f, 0.f};
  f32x4 acc[2][2][2][4];
#pragma unroll
  for (int a = 0; a < 2; ++a)
#pragma unroll
    for (int b = 0; b < 2; ++b)
#pragma unroll
      for (int c = 0; c < 2; ++c)
#pragma unroll
        for (int d = 0; d < 4; ++d) acc[a][b][c][d] = fzero;

  gemm_core<1024, 32>(Ag, Bg, lds, acc, t);

  const float* b2m = b2 + m * 512;
  const bf16* Xm = Xb + (size_t)m * (1024 * 512);
#pragma unroll
  for (int qc = 0; qc < 2; ++qc)
#pragma unroll
    for (int fj = 0; fj < 4; ++fj) {
      const int b_ = bb * 256 + qc * 128 + (wid >> 2) * 64 + fj * 16 + llo;
      const int n_out = inv[b_ * 32 + m];
      float* orow = out + ((size_t)b_ * 32 + n_out) * 512;
      const bf16* xrow = Xm + (size_t)b_ * 512;
#pragma unroll
      for (int qr = 0; qr < 2; ++qr)
#pragma unroll
        for (int fi = 0; fi < 2; ++fi) {
          const int d0 = db_ * 256 + qr * 128 + (wid & 3) * 32 + fi * 16 + lhi * 4;
          const float4 bi = *(const float4*)&b2m[d0];
          const ushort4 xr = *(const ushort4*)&xrow[d0];
          float4 v;
          v.x = acc[qr][qc][fi][fj][0] + bi.x + bf2f(xr.x);
          v.y = acc[qr][qc][fi][fj][1] + bi.y + bf2f(xr.y);
          v.z = acc[qr][qc][fi][fj][2] + bi.z + bf2f(xr.z);
          v.w = acc[qr][qc][fi][fj][3] + bi.w + bf2f(xr.w);
          *(float4*)&orow[d0] = v;
        }
    }
}

// ---------------------------------------------------------------------------
extern "C" void kernel_launch(void* const* d_in, const int* in_sizes, int n_in,
                              void* d_out, int out_size, void* d_ws, size_t ws_size,
                              hipStream_t stream) {
  const float* z     = (const float*)d_in[0];
  const int*   idx   = (const int*)d_in[1];
  const float* A     = (const float*)d_in[2];
  const float* W1    = (const float*)d_in[3];
  const float* b1    = (const float*)d_in[4];
  const float* W2    = (const float*)d_in[5];
  const float* b2    = (const float*)d_in[6];
  const float* gamma = (const float*)d_in[7];
  const float* beta  = (const float*)d_in[8];
  float* out = (float*)d_out;
  char* ws = (char*)d_ws;

  const size_t OFF_X   = 0;           // bf16 [32][1024][512]  : 32 MiB
  const size_t OFF_H   = 33554432;    // bf16 [32][1024][1024] : 64 MiB
  const size_t OFF_W1T = 100663296;   // bf16 [32][1024][512]  : 32 MiB
  const size_t OFF_W2T = 134217728;   // bf16 [32][512][1024]  : 32 MiB
  const size_t OFF_INV = 167772160;   // int  [1024][32]       : 128 KiB
  const size_t NEED    = 167903232;
  if (ws_size < NEED) return;

  bf16* Xb  = (bf16*)(ws + OFF_X);
  bf16* Hb  = (bf16*)(ws + OFF_H);
  bf16* W1t = (bf16*)(ws + OFF_W1T);
  bf16* W2t = (bf16*)(ws + OFF_W2T);
  int*  inv = (int*)(ws + OFF_INV);

  hipFuncSetAttribute((const void*)gemm1_kernel,
                      hipFuncAttributeMaxDynamicSharedMemorySize, 65536);
  hipFuncSetAttribute((const void*)gemm2_kernel,
                      hipFuncAttributeMaxDynamicSharedMemorySize, 65536);

  // fused prep: W1t + W2t transposes and mix+LN in one dispatch
  prep_kernel<<<dim3(9216), 256, 0, stream>>>(W1, W2, W1t, W2t,
                                              z, idx, A, gamma, beta, Xb, inv);

  gemm1_kernel<<<dim3(512), 512, 65536, stream>>>(Xb, W1t, b1, Hb);
  gemm2_kernel<<<dim3(256), 512, 65536, stream>>>(Hb, W2t, b2, Xb, inv, out);
}

// Round 17
// 161.443 us; speedup vs baseline: 1.0853x; 1.0176x over previous
//
#include <hip/hip_runtime.h>
#include <hip/hip_bf16.h>
#include <math.h>

// Problem constants
#define B_  1024
#define N_  32
#define D_  512
#define EPS_ 1e-5f

typedef __attribute__((ext_vector_type(8))) short bf16x8;   // 8 bf16 = 4 VGPRs
typedef __attribute__((ext_vector_type(4))) float f32x4;
using bf16 = __hip_bfloat16;
typedef unsigned int u32;
typedef const u32 __attribute__((address_space(1)))* gp_t;
typedef u32 __attribute__((address_space(3)))* sp_t;

// async global->LDS, 16 B per lane, lds dest = wave-uniform base + lane*16
static __device__ __forceinline__ void gload16(const void* g, void* s) {
  __builtin_amdgcn_global_load_lds((gp_t)g, (sp_t)s, 16, 0, 0);
}
static __device__ __forceinline__ void bar() {
  asm volatile("s_barrier" ::: "memory");
}

static __device__ __forceinline__ unsigned short f2bf(float f) {
  union { float f; u32 u; } c; c.f = f;
  u32 r = c.u + 0x7fff + ((c.u >> 16) & 1);   // RNE
  return (unsigned short)(r >> 16);
}
static __device__ __forceinline__ float bf2f(unsigned short h) {
  union { u32 u; float f; } c; c.u = ((u32)h) << 16;
  return c.f;
}

// ---------------------------------------------------------------------------
// Fused prep (measured best: fused 167.2 vs separate 175.2): one dispatch
// does W1 transpose (blocks 0..4095), W2 transpose (4096..8191), mix+LN
// (8192..9215). Prep is ~50us vs 46us HBM floor -- done.
// ---------------------------------------------------------------------------
static __device__ __forceinline__ void transpose_tile(
    const float* __restrict__ in, bf16* __restrict__ out,
    int R, int C, int bx, int by, int bz, int t) {
  __shared__ unsigned short tile[64][65];
  const size_t mat = (size_t)bz * (size_t)R * (size_t)C;
  const float* inp = in + mat;
  bf16* outp = out + mat;
  const int c0 = bx * 64, r0 = by * 64;
  const int tr = t >> 4;           // 0..15
  const int tc = (t & 15) * 4;     // 0,4,..,60
#pragma unroll
  for (int i = 0; i < 4; ++i) {
    const int r = tr + i * 16;
    float4 v = *(const float4*)&inp[(size_t)(r0 + r) * C + c0 + tc];
    tile[r][tc + 0] = f2bf(v.x);
    tile[r][tc + 1] = f2bf(v.y);
    tile[r][tc + 2] = f2bf(v.z);
    tile[r][tc + 3] = f2bf(v.w);
  }
  __syncthreads();
#pragma unroll
  for (int i = 0; i < 2; ++i) {
    const int chunk = i * 256 + t;
    const int c = chunk >> 3, r8 = (chunk & 7) * 8;
    union { bf16x8 v; unsigned short u[8]; } pk;
#pragma unroll
    for (int k = 0; k < 8; ++k) pk.u[k] = tile[r8 + k][c];
    *(bf16x8*)&outp[(size_t)(c0 + c) * R + r0 + r8] = pk.v;
  }
}

static __device__ __forceinline__ void mix_ln_body(
    int b, int t,
    const float* __restrict__ z, const int* __restrict__ idx,
    const float* __restrict__ A, const float* __restrict__ gamma,
    const float* __restrict__ beta, bf16* __restrict__ x_ws,
    int* __restrict__ inv_ws) {
  __shared__ float As[32][32];      // As[k][n] = A[p[k]][n]
  __shared__ int   p[32];
  __shared__ float red1[4][32];
  __shared__ float red2[4][32];
  __shared__ float meanS[32];
  __shared__ float rstdS[32];

  const int lane = t & 63, wid = t >> 6;      // 4 waves
  const int llo = lane & 15, lhi = lane >> 4; // col-lane / row-group

  if (t < 32) {
    int v = idx[b * 32 + t];
    p[t] = v;
    inv_ws[b * 32 + v] = t;
  }
  __syncthreads();
#pragma unroll
  for (int i = 0; i < 4; ++i) {
    const int id = i * 256 + t;
    As[id >> 5][id & 31] = A[p[id >> 5] * 32 + (id & 31)];
  }
  __syncthreads();

  bf16x8 af[2];
#pragma unroll
  for (int nt = 0; nt < 2; ++nt) {
    union { bf16x8 v; unsigned short s[8]; } u;
#pragma unroll
    for (int j = 0; j < 8; ++j)
      u.s[j] = f2bf(As[lhi * 8 + j][nt * 16 + llo]);
    af[nt] = u.v;
  }

  const float* zb = z + (size_t)b * (N_ * D_) + (size_t)(lhi * 8) * D_ + llo;
  const f32x4 fz = {0.f, 0.f, 0.f, 0.f};
  f32x4 acc[2][8];
#pragma unroll
  for (int nt = 0; nt < 2; ++nt)
#pragma unroll
    for (int dt = 0; dt < 8; ++dt) acc[nt][dt] = fz;

#pragma unroll
  for (int h = 0; h < 2; ++h) {
    float zr[4][8];
#pragma unroll
    for (int dd = 0; dd < 4; ++dd)
#pragma unroll
      for (int j = 0; j < 8; ++j)
        zr[dd][j] = zb[j * D_ + ((wid * 8 + h * 4 + dd) * 16)];
#pragma unroll
    for (int dd = 0; dd < 4; ++dd) {
      const int dt = h * 4 + dd;
      union { bf16x8 v; unsigned short s[8]; } u;
#pragma unroll
      for (int j = 0; j < 8; ++j) u.s[j] = f2bf(zr[dd][j]);
      acc[0][dt] = __builtin_amdgcn_mfma_f32_16x16x32_bf16(af[0], u.v, acc[0][dt], 0, 0, 0);
      acc[1][dt] = __builtin_amdgcn_mfma_f32_16x16x32_bf16(af[1], u.v, acc[1][dt], 0, 0, 0);
    }
  }

  float s1[2][4], s2[2][4];
#pragma unroll
  for (int nt = 0; nt < 2; ++nt)
#pragma unroll
    for (int r = 0; r < 4; ++r) {
      float a = 0.f, q = 0.f;
#pragma unroll
      for (int dt = 0; dt < 8; ++dt) {
        float v = acc[nt][dt][r];
        a += v; q += v * v;
      }
#pragma unroll
      for (int mk = 1; mk < 16; mk <<= 1) {
        a += __shfl_xor(a, mk);
        q += __shfl_xor(q, mk);
      }
      s1[nt][r] = a; s2[nt][r] = q;
    }
  if (llo == 0) {
#pragma unroll
    for (int nt = 0; nt < 2; ++nt)
#pragma unroll
      for (int r = 0; r < 4; ++r) {
        const int n = nt * 16 + lhi * 4 + r;
        red1[wid][n] = s1[nt][r];
        red2[wid][n] = s2[nt][r];
      }
  }
  __syncthreads();
  if (t < 32) {
    float S1 = red1[0][t] + red1[1][t] + red1[2][t] + red1[3][t];
    float S2 = red2[0][t] + red2[1][t] + red2[2][t] + red2[3][t];
    float mean = S1 * (1.f / D_);
    float var  = S2 * (1.f / D_) - mean * mean;
    meanS[t] = mean;
    rstdS[t] = rsqrtf(var + EPS_);
  }
  __syncthreads();

  float gv[8], bev[8];
#pragma unroll
  for (int dt = 0; dt < 8; ++dt) {
    const int d = (wid * 8 + dt) * 16 + llo;
    gv[dt] = gamma[d]; bev[dt] = beta[d];
  }
#pragma unroll
  for (int nt = 0; nt < 2; ++nt)
#pragma unroll
    for (int r = 0; r < 4; ++r) {
      const int n = nt * 16 + lhi * 4 + r;
      const float mn = meanS[n], rs = rstdS[n];
      unsigned short* xrow = (unsigned short*)(x_ws + ((size_t)n * B_ + b) * D_);
#pragma unroll
      for (int dt = 0; dt < 8; ++dt) {
        const int d = (wid * 8 + dt) * 16 + llo;
        float v = (acc[nt][dt][r] - mn) * rs * gv[dt] + bev[dt];
        xrow[d] = f2bf(v);
      }
    }
}

__global__ __launch_bounds__(256) void prep_kernel(
    const float* __restrict__ W1, const float* __restrict__ W2,
    bf16* __restrict__ W1t, bf16* __restrict__ W2t,
    const float* __restrict__ z, const int* __restrict__ idx,
    const float* __restrict__ A, const float* __restrict__ gamma,
    const float* __restrict__ beta, bf16* __restrict__ x_ws,
    int* __restrict__ inv_ws) {
  const int bid = blockIdx.x;
  const int t = threadIdx.x;
  if (bid < 4096) {
    // W1 [32][512][1024] -> W1t [32][1024][512]
    transpose_tile(W1, W1t, 512, 1024, bid & 15, (bid >> 4) & 7, bid >> 7, t);
  } else if (bid < 8192) {
    // W2 [32][1024][512] -> W2t [32][512][1024]
    const int b2 = bid - 4096;
    transpose_tile(W2, W2t, 1024, 512, b2 & 7, (b2 >> 3) & 15, b2 >> 7, t);
  } else {
    mix_ln_body(bid - 8192, t, z, idx, A, gamma, beta, x_ws, inv_ws);
  }
}

// ---------------------------------------------------------------------------
// 256x256 GEMM core, BK=32, 8 waves, 64KB LDS, fat fragments, 1 barrier per
// subtile (r16 schedule) + NEW: k-slot bank swizzle (row>>1)&3, BOTH sides.
// Mechanism: unswizzled 64B rows put a 16-lane b128 read group on 2 banks
// (8-way conflict, 2.94x -- LDS pipe was the binding resource, explaining
// MfmaUtil stuck at 24% and SQ_LDS_BANK_CONFLICT ~5x read count). The
// permuted slot kx = (lhi ^ ((llo>>1)&3))*16 spreads the group over 8 banks
// (2-way = free). Write side pre-permutes the GLOBAL source (gload_lds
// writes LDS linearly): soff slot = (t&3) ^ ((t>>3)&3). Involution-verified.
// LDS: A parity p at p*16K (halves 8K = 128 rows of 64B); B at 32K + p*16K.
// ---------------------------------------------------------------------------
#define STGA(P, H, S)                                                         \
  gload16(Ag + (size_t)((H) * 128) * KD + (S) * 32 + soff,                    \
          lds + (P) * 16384 + (H) * 8192 + dof)
#define STGB(P, H, S)                                                         \
  gload16(Bg + (size_t)((H) * 128) * KD + (S) * 32 + soff,                    \
          lds + 32768 + (P) * 16384 + (H) * 8192 + dof)

#define RDA(P, H, AV) do {                                                    \
    const char* a_ = lds + (P) * 16384 + (H) * 8192;                          \
    AV[0] = *(const bf16x8*)(a_ + (widA * 32 + llo) * 64 + kx);               \
    AV[1] = *(const bf16x8*)(a_ + (widA * 32 + 16 + llo) * 64 + kx);          \
  } while (0)
#define RDB(P, H, BV) do {                                                    \
    const char* b_ = lds + 32768 + (P) * 16384 + (H) * 8192;                  \
    _Pragma("unroll")                                                         \
    for (int fj = 0; fj < 4; ++fj)                                            \
      BV[fj] = *(const bf16x8*)(b_ + (widB * 64 + fj * 16 + llo) * 64 + kx);  \
  } while (0)

#define MMA8(QR, QC, AV, BV) do {                                             \
    __builtin_amdgcn_s_setprio(1);                                            \
    _Pragma("unroll")                                                         \
    for (int fi = 0; fi < 2; ++fi)                                            \
      _Pragma("unroll")                                                       \
      for (int fj = 0; fj < 4; ++fj)                                          \
        acc[QR][QC][fi][fj] = __builtin_amdgcn_mfma_f32_16x16x32_bf16(        \
            AV[fi], BV[fj], acc[QR][QC][fi][fj], 0, 0, 0);                    \
    __builtin_amdgcn_s_setprio(0);                                            \
  } while (0)

#define VMC0() asm volatile("s_waitcnt vmcnt(0)" ::: "memory")

// 1-barrier subtile. Hazards: RAW -- buffer P^1 (subtile s+1) was staged at
// s-1's STG; this subtile's VMC0 drains it and bar publishes it before s+1's
// reads. WAR -- STG into P is after bar, by which all waves finished RD(P).
#define SUBTILE(P, S) do {                                                    \
    bf16x8 av[2], bv0[4], bv1[4];                                             \
    RDA(P, 0, av); RDB(P, 0, bv0); RDB(P, 1, bv1);                            \
    MMA8(0, 0, av, bv0);                                                      \
    MMA8(0, 1, av, bv1);                                                      \
    RDA(P, 1, av);                                                            \
    MMA8(1, 0, av, bv0);                                                      \
    MMA8(1, 1, av, bv1);                                                      \
    VMC0();                                 /* s+1's loads (1 subtile old) */ \
    bar();                                  /* publish s+1; reads of P done */\
    if ((S) + 2 < NS) {                                                       \
      STGA(P, 0, (S) + 2); STGA(P, 1, (S) + 2);                               \
      STGB(P, 0, (S) + 2); STGB(P, 1, (S) + 2);                               \
    }                                                                         \
  } while (0)

template <int KD, int NS>
static __device__ __forceinline__ void gemm_core(
    const bf16* __restrict__ Ag, const bf16* __restrict__ Bg,
    char* __restrict__ lds, f32x4 (&acc)[2][2][2][4], const int t) {
  const int lane = t & 63, wid = t >> 6;
  const int llo = lane & 15, lhi = lane >> 4;
  const int widA = wid & 3, widB = wid >> 2;
  // bank-swizzled k-slot: slot = lhi ^ ((row>>1)&3); row>>1&3 == llo>>1&3
  // for every A/B fragment row this lane touches (offsets are mult. of 16).
  const int kx = (lhi ^ ((llo >> 1) & 3)) * 16;
  // stage source: LDS slot (t&3) receives global slot (t&3)^((row>>1)&3),
  // row = t>>2 -> p = (t>>3)&3.
  const size_t soff = (size_t)(t >> 2) * KD + (size_t)(((t & 3) ^ ((t >> 3) & 3))) * 8;
  const int dof = wid * 1024;                          // stage LDS dest (bytes)

  // prologue: stage subtiles 0 and 1 fully; drain; publish
  STGA(0, 0, 0); STGA(0, 1, 0); STGB(0, 0, 0); STGB(0, 1, 0);
  STGA(1, 0, 1); STGA(1, 1, 1); STGB(1, 0, 1); STGB(1, 1, 1);
  VMC0();
  bar();

#pragma unroll 1
  for (int it = 0; it < NS / 2; ++it) {
    SUBTILE(0, 2 * it);
    SUBTILE(1, 2 * it + 1);
  }
}

// ---------------------------------------------------------------------------
// GEMM1: C[h][b] = W1t[h][:] . X[b][:] (K=512), bias+ELU -> H[b][h] bf16.
// 256x256 tile; epilogue via LDS in two compile-time 64KB passes.
// grid 512 = 32m*4hb*4bb, XCD-swizzled.
// ---------------------------------------------------------------------------
#define EPI(QC) do {                                                          \
    __syncthreads();                                                          \
    _Pragma("unroll")                                                         \
    for (int qr = 0; qr < 2; ++qr)                                            \
      _Pragma("unroll")                                                       \
      for (int fi = 0; fi < 2; ++fi) {                                        \
        const int h_loc = qr * 128 + (wid & 3) * 32 + fi * 16 + lhi * 4;      \
        const float4 bi = *(const float4*)&b1m[h_loc];                        \
        _Pragma("unroll")                                                     \
        for (int fj = 0; fj < 4; ++fj) {                                      \
          const int b_loc = (wid >> 2) * 64 + fj * 16 + llo;                  \
          float v0 = acc[qr][QC][fi][fj][0] + bi.x;                           \
          float v1 = acc[qr][QC][fi][fj][1] + bi.y;                           \
          float v2 = acc[qr][QC][fi][fj][2] + bi.z;                           \
          float v3 = acc[qr][QC][fi][fj][3] + bi.w;                           \
          v0 = v0 > 0.f ? v0 : __expf(v0) - 1.0f;                             \
          v1 = v1 > 0.f ? v1 : __expf(v1) - 1.0f;                             \
          v2 = v2 > 0.f ? v2 : __expf(v2) - 1.0f;                             \
          v3 = v3 > 0.f ? v3 : __expf(v3) - 1.0f;                             \
          ushort4 pk;                                                         \
          pk.x = f2bf(v0); pk.y = f2bf(v1); pk.z = f2bf(v2); pk.w = f2bf(v3); \
          const int byte = (b_loc * 512 + h_loc * 2) ^ ((b_loc & 7) << 4);    \
          *(ushort4*)(lds + byte) = pk;                                       \
        }                                                                     \
      }                                                                       \
    __syncthreads();                                                          \
    _Pragma("unroll")                                                         \
    for (int i = 0; i < 8; ++i) {                                             \
      const int c = i * 512 + t;                                              \
      const int bl = c >> 5, hc = c & 31;                                     \
      const int byte = (bl * 512 + hc * 16) ^ ((bl & 7) << 4);                \
      bf16x8 v = *(const bf16x8*)(lds + byte);                                \
      *(bf16x8*)&Hm[(size_t)(b0 + (QC) * 128 + bl) * 1024 + h0 + hc * 8] = v; \
    }                                                                         \
  } while (0)

__global__ __launch_bounds__(512, 2) void gemm1_kernel(
    const bf16* __restrict__ X,    // [32][1024][512]
    const bf16* __restrict__ W1t,  // [32][1024][512]
    const float* __restrict__ b1,  // [32][1024]
    bf16* __restrict__ Hout) {     // [32][1024][1024]
  extern __shared__ char lds[];

  const int bid = blockIdx.x;
  const int swz = (bid & 7) * 64 + (bid >> 3);   // nwg=512, bijective
  const int m  = swz >> 4;
  const int r_ = swz & 15;
  const int hb = r_ >> 2, bb = r_ & 3;

  const int t = threadIdx.x;
  const int lane = t & 63, wid = t >> 6;
  const int llo = lane & 15, lhi = lane >> 4;

  const bf16* Ag = W1t + (size_t)m * (1024 * 512) + (size_t)(hb * 256) * 512;
  const bf16* Bg = X   + (size_t)m * (1024 * 512) + (size_t)(bb * 256) * 512;

  const f32x4 fzero = {0.f, 0.f, 0.f, 0.f};
  f32x4 acc[2][2][2][4];
#pragma unroll
  for (int a = 0; a < 2; ++a)
#pragma unroll
    for (int b = 0; b < 2; ++b)
#pragma unroll
      for (int c = 0; c < 2; ++c)
#pragma unroll
        for (int d = 0; d < 4; ++d) acc[a][b][c][d] = fzero;

  gemm_core<512, 16>(Ag, Bg, lds, acc, t);

  bf16* Hm = Hout + (size_t)m * (1024 * 1024);
  const float* b1m = b1 + m * 1024 + hb * 256;
  const int b0 = bb * 256, h0 = hb * 256;
  EPI(0);
  EPI(1);
}

// ---------------------------------------------------------------------------
// GEMM2: C[d][b] = W2t[d][:] . H[b][:] (K=1024);
// out[b][inv[b][m]][d] = C + b2 + x via float4 stores.
// 256x256 tile; grid 256 = 32m * 2db * 4bb, XCD-swizzled.
// ---------------------------------------------------------------------------
__global__ __launch_bounds__(512, 2) void gemm2_kernel(
    const bf16* __restrict__ Hin,  // [32][1024][1024]
    const bf16* __restrict__ W2t,  // [32][512][1024]
    const float* __restrict__ b2,  // [32][512]
    const bf16* __restrict__ Xb,   // [32][1024][512]
    const int* __restrict__ inv,   // [1024][32]
    float* __restrict__ out) {     // [1024][32][512]
  extern __shared__ char lds[];

  const int bid = blockIdx.x;
  const int swz = (bid & 7) * 32 + (bid >> 3);   // nwg=256, bijective
  const int m  = swz >> 3;
  const int r_ = swz & 7;
  const int db_ = r_ >> 2, bb = r_ & 3;

  const int t = threadIdx.x;
  const int lane = t & 63, wid = t >> 6;
  const int llo = lane & 15, lhi = lane >> 4;

  const bf16* Ag = W2t + (size_t)m * (512 * 1024) + (size_t)(db_ * 256) * 1024;
  const bf16* Bg = Hin + (size_t)m * (1024 * 1024) + (size_t)(bb * 256) * 1024;

  const f32x4 fzero = {0.f, 0.f, 0.f, 0.f};
  f32x4 acc[2][2][2][4];
#pragma unroll
  for (int a = 0; a < 2; ++a)
#pragma unroll
    for (int b = 0; b < 2; ++b)
#pragma unroll
      for (int c = 0; c < 2; ++c)
#pragma unroll
        for (int d = 0; d < 4; ++d) acc[a][b][c][d] = fzero;

  gemm_core<1024, 32>(Ag, Bg, lds, acc, t);

  const float* b2m = b2 + m * 512;
  const bf16* Xm = Xb + (size_t)m * (1024 * 512);
#pragma unroll
  for (int qc = 0; qc < 2; ++qc)
#pragma unroll
    for (int fj = 0; fj < 4; ++fj) {
      const int b_ = bb * 256 + qc * 128 + (wid >> 2) * 64 + fj * 16 + llo;
      const int n_out = inv[b_ * 32 + m];
      float* orow = out + ((size_t)b_ * 32 + n_out) * 512;
      const bf16* xrow = Xm + (size_t)b_ * 512;
#pragma unroll
      for (int qr = 0; qr < 2; ++qr)
#pragma unroll
        for (int fi = 0; fi < 2; ++fi) {
          const int d0 = db_ * 256 + qr * 128 + (wid & 3) * 32 + fi * 16 + lhi * 4;
          const float4 bi = *(const float4*)&b2m[d0];
          const ushort4 xr = *(const ushort4*)&xrow[d0];
          float4 v;
          v.x = acc[qr][qc][fi][fj][0] + bi.x + bf2f(xr.x);
          v.y = acc[qr][qc][fi][fj][1] + bi.y + bf2f(xr.y);
          v.z = acc[qr][qc][fi][fj][2] + bi.z + bf2f(xr.z);
          v.w = acc[qr][qc][fi][fj][3] + bi.w + bf2f(xr.w);
          *(float4*)&orow[d0] = v;
        }
    }
}

// ---------------------------------------------------------------------------
extern "C" void kernel_launch(void* const* d_in, const int* in_sizes, int n_in,
                              void* d_out, int out_size, void* d_ws, size_t ws_size,
                              hipStream_t stream) {
  const float* z     = (const float*)d_in[0];
  const int*   idx   = (const int*)d_in[1];
  const float* A     = (const float*)d_in[2];
  const float* W1    = (const float*)d_in[3];
  const float* b1    = (const float*)d_in[4];
  const float* W2    = (const float*)d_in[5];
  const float* b2    = (const float*)d_in[6];
  const float* gamma = (const float*)d_in[7];
  const float* beta  = (const float*)d_in[8];
  float* out = (float*)d_out;
  char* ws = (char*)d_ws;

  const size_t OFF_X   = 0;           // bf16 [32][1024][512]  : 32 MiB
  const size_t OFF_H   = 33554432;    // bf16 [32][1024][1024] : 64 MiB
  const size_t OFF_W1T = 100663296;   // bf16 [32][1024][512]  : 32 MiB
  const size_t OFF_W2T = 134217728;   // bf16 [32][512][1024]  : 32 MiB
  const size_t OFF_INV = 167772160;   // int  [1024][32]       : 128 KiB
  const size_t NEED    = 167903232;
  if (ws_size < NEED) return;

  bf16* Xb  = (bf16*)(ws + OFF_X);
  bf16* Hb  = (bf16*)(ws + OFF_H);
  bf16* W1t = (bf16*)(ws + OFF_W1T);
  bf16* W2t = (bf16*)(ws + OFF_W2T);
  int*  inv = (int*)(ws + OFF_INV);

  hipFuncSetAttribute((const void*)gemm1_kernel,
                      hipFuncAttributeMaxDynamicSharedMemorySize, 65536);
  hipFuncSetAttribute((const void*)gemm2_kernel,
                      hipFuncAttributeMaxDynamicSharedMemorySize, 65536);

  // fused prep: W1t + W2t transposes and mix+LN in one dispatch
  prep_kernel<<<dim3(9216), 256, 0, stream>>>(W1, W2, W1t, W2t,
                                              z, idx, A, gamma, beta, Xb, inv);

  gemm1_kernel<<<dim3(512), 512, 65536, stream>>>(Xb, W1t, b1, Hb);
  gemm2_kernel<<<dim3(256), 512, 65536, stream>>>(Hb, W2t, b2, Xb, inv, out);
}